// Round 1
// baseline (279.835 us; speedup 1.0000x reference)
//
#include <hip/hip_runtime.h>

#define U_ 100000
#define I_ 100000
#define D_ 64
#define L_ 50
#define B_ 4096
#define T_ 100

__device__ __forceinline__ float sigmoidf_(float x) {
    return 1.0f / (1.0f + __expf(-x));
}

// Kernel 1: per-b combined vector v[b] = user_emb + union_out + sum_l item_embs
// One wave (64 lanes) per b; lane = feature dim d.
__global__ __launch_bounds__(256) void hgn_user_kernel(
    const int* __restrict__ item_seq,         // [B,L]
    const int* __restrict__ user_ids,         // [B]
    const float* __restrict__ user_emb_table, // [U,D]
    const float* __restrict__ item_emb_table, // [I,D]
    const float* __restrict__ fg_item_W,      // [D,D]
    const float* __restrict__ fg_item_b,      // [D]
    const float* __restrict__ fg_user_W,      // [D,D]
    const float* __restrict__ fg_user_b,      // [D]
    const float* __restrict__ ig_item,        // [D,1]
    const float* __restrict__ ig_user,        // [D,L]
    float* __restrict__ v_out)                // [B,D]
{
    const int lane = threadIdx.x & 63;
    const int wave = threadIdx.x >> 6;
    const int b = blockIdx.x * 4 + wave;

    // fg_item_W column `lane` into registers: Wreg[k] = W[k][lane]
    float Wreg[64];
#pragma unroll
    for (int k = 0; k < 64; ++k) Wreg[k] = fg_item_W[k * 64 + lane];

    const int uid = user_ids[b];                       // wave-uniform
    const float* urow = user_emb_table + (size_t)uid * D_;
    const float u = urow[lane];

    // gate bias per-dim: fg_item_b + fg_user_b + u @ fg_user_W
    float gbias = fg_item_b[lane] + fg_user_b[lane];
#pragma unroll
    for (int kk = 0; kk < 16; ++kk) {
        const float4 u4 = ((const float4*)urow)[kk];   // lane-uniform broadcast
        gbias = fmaf(u4.x, fg_user_W[(4 * kk + 0) * 64 + lane], gbias);
        gbias = fmaf(u4.y, fg_user_W[(4 * kk + 1) * 64 + lane], gbias);
        gbias = fmaf(u4.z, fg_user_W[(4 * kk + 2) * 64 + lane], gbias);
        gbias = fmaf(u4.w, fg_user_W[(4 * kk + 3) * 64 + lane], gbias);
    }

    const float igi = ig_item[lane];

    float acc = 0.f, esum = 0.f, ssum = 0.f;
    for (int l = 0; l < L_; ++l) {
        const int idx = item_seq[b * L_ + l];          // wave-uniform
        const float* row = item_emb_table + (size_t)idx * D_;
        const float e = row[lane];

        // gate input: row @ fg_item_W (column `lane`) + gbias
        float g = gbias;
#pragma unroll
        for (int kk = 0; kk < 16; ++kk) {
            const float4 e4 = ((const float4*)row)[kk]; // lane-uniform broadcast
            g = fmaf(e4.x, Wreg[4 * kk + 0], g);
            g = fmaf(e4.y, Wreg[4 * kk + 1], g);
            g = fmaf(e4.z, Wreg[4 * kk + 2], g);
            g = fmaf(e4.w, Wreg[4 * kk + 3], g);
        }
        const float gate = sigmoidf_(g);
        const float gi = e * gate;

        // instance score: sum_d(gi*ig_item) + sum_d(u*ig_user[d][l])
        float p = fmaf(gi, igi, u * ig_user[lane * L_ + l]);
#pragma unroll
        for (int off = 32; off >= 1; off >>= 1) p += __shfl_xor(p, off, 64);
        const float s = sigmoidf_(p);

        acc = fmaf(gi, s, acc);
        ssum += s;
        esum += e;
    }

    v_out[b * D_ + lane] = u + acc / ssum + esum;
}

// Kernel 2: res[b,t] = b2[idx] + dot(W2[idx], v[b]).
// One lane per (b,t); 2 waves cover T=100 per b (second wave 36 active lanes).
__global__ __launch_bounds__(256) void hgn_score_kernel(
    const int* __restrict__ items_to_predict, // [B,T]
    const float* __restrict__ W2,             // [I,D]
    const float* __restrict__ b2,             // [I]
    const float* __restrict__ v,              // [B,D]
    float* __restrict__ out)                  // [B,T]
{
    const int lane = threadIdx.x & 63;
    const int wtask = (int)((blockIdx.x * 256 + threadIdx.x) >> 6); // global wave id
    const int b = wtask >> 1;
    const int t = ((wtask & 1) << 6) + lane;
    const bool valid = t < T_;

    const int idx = valid ? items_to_predict[b * T_ + t] : 0;
    const float* wrow = W2 + (size_t)idx * D_;
    const float* vrow = v + b * D_;

    float r = 0.f;
#pragma unroll
    for (int kk = 0; kk < 16; ++kk) {
        const float4 v4 = ((const float4*)vrow)[kk];  // lane-uniform broadcast
        const float4 w4 = ((const float4*)wrow)[kk];  // per-lane row gather
        r = fmaf(v4.x, w4.x, r);
        r = fmaf(v4.y, w4.y, r);
        r = fmaf(v4.z, w4.z, r);
        r = fmaf(v4.w, w4.w, r);
    }
    if (valid) out[b * T_ + t] = r + b2[idx];
}

extern "C" void kernel_launch(void* const* d_in, const int* in_sizes, int n_in,
                              void* d_out, int out_size, void* d_ws, size_t ws_size,
                              hipStream_t stream) {
    const int*   item_seq   = (const int*)d_in[0];
    const int*   user_ids   = (const int*)d_in[1];
    const int*   items_pred = (const int*)d_in[2];
    const float* uet        = (const float*)d_in[3];
    const float* iet        = (const float*)d_in[4];
    const float* fgiW       = (const float*)d_in[5];
    const float* fgib       = (const float*)d_in[6];
    const float* fguW       = (const float*)d_in[7];
    const float* fgub       = (const float*)d_in[8];
    const float* igi        = (const float*)d_in[9];
    const float* igu        = (const float*)d_in[10];
    const float* W2         = (const float*)d_in[11];
    const float* b2t        = (const float*)d_in[12];

    float* out = (float*)d_out;
    float* v   = (float*)d_ws;   // [B, D] f32 = 1 MB scratch

    // Kernel 1: 4096 waves, one per b -> 1024 blocks of 256.
    hgn_user_kernel<<<B_ / 4, 256, 0, stream>>>(
        item_seq, user_ids, uet, iet, fgiW, fgib, fguW, fgub, igi, igu, v);

    // Kernel 2: 2 waves per b -> 8192 waves -> 2048 blocks of 256.
    hgn_score_kernel<<<(B_ * 2) / 4, 256, 0, stream>>>(
        items_pred, W2, b2t, v, out);
}

// Round 2
// 273.610 us; speedup vs baseline: 1.0228x; 1.0228x over previous
//
#include <hip/hip_runtime.h>

#define D_ 64
#define L_ 50
#define B_ 4096
#define T_ 100

__device__ __forceinline__ float sigmoidf_(float x) {
    return 1.0f / (1.0f + __expf(-x));
}

// One block (4 waves) per batch element b.
// Phase A: gating -> gi[l][d] in LDS (l split across waves, lane = d)
// Phase B: instance scores s[l] (wave 0, lane = l, LDS dots; no shuffles)
// Phase C: v[d] = u + union_out + sum_l e  (wave 0, lane = d)
// Phase D: res[b,t] = b2[idx] + dot(W2[idx], v)  (threads t < 100)
__global__ __launch_bounds__(256, 4) void hgn_fused_kernel(
    const int* __restrict__ item_seq,          // [B,L]
    const int* __restrict__ user_ids,          // [B]
    const int* __restrict__ items_to_predict,  // [B,T]
    const float* __restrict__ user_emb_table,  // [U,D]
    const float* __restrict__ item_emb_table,  // [I,D]
    const float* __restrict__ fg_item_W,       // [D,D]
    const float* __restrict__ fg_item_b,       // [D]
    const float* __restrict__ fg_user_W,       // [D,D]
    const float* __restrict__ fg_user_b,       // [D]
    const float* __restrict__ ig_item,         // [D]
    const float* __restrict__ ig_user,         // [D,L]
    const float* __restrict__ W2,              // [I,D]
    const float* __restrict__ b2,              // [I]
    float* __restrict__ out)                   // [B,T]
{
    __shared__ float gi_sh[L_ * 65];           // padded stride 65: conflict-free
    __shared__ float s_sh[L_];
    __shared__ __align__(16) float u_sh[D_];
    __shared__ __align__(16) float v_sh[D_];
    __shared__ float esum_sh[4 * D_];
    __shared__ int   idx_sh[L_];

    const int t    = threadIdx.x;
    const int lane = t & 63;
    const int wave = t >> 6;
    const int b    = blockIdx.x;

    const int uid = user_ids[b];                         // block-uniform
    const float* urow = user_emb_table + (size_t)uid * D_;

    if (t < L_) idx_sh[t] = item_seq[b * L_ + t];
    if (t >= 64 && t < 128) u_sh[t - 64] = urow[t - 64];

    // fg_item_W column `lane` into registers (L1-hot after first blocks)
    float Wreg[64];
#pragma unroll
    for (int k = 0; k < 64; ++k) Wreg[k] = fg_item_W[k * 64 + lane];

    // per-dim gate bias: fg_item_b + fg_user_b + u @ fg_user_W   (4 chains)
    float gb0 = fg_item_b[lane], gb1 = fg_user_b[lane], gb2 = 0.f, gb3 = 0.f;
#pragma unroll
    for (int kk = 0; kk < 16; ++kk) {
        const float4 u4 = ((const float4*)urow)[kk];     // lane-uniform broadcast
        gb0 = fmaf(u4.x, fg_user_W[(4 * kk + 0) * 64 + lane], gb0);
        gb1 = fmaf(u4.y, fg_user_W[(4 * kk + 1) * 64 + lane], gb1);
        gb2 = fmaf(u4.z, fg_user_W[(4 * kk + 2) * 64 + lane], gb2);
        gb3 = fmaf(u4.w, fg_user_W[(4 * kk + 3) * 64 + lane], gb3);
    }
    const float gbias = (gb0 + gb1) + (gb2 + gb3);

    __syncthreads();   // idx_sh / u_sh ready

    // ---- Phase A: gating; wave handles l = wave, wave+4, ...
    float esum = 0.f;
    for (int l = wave; l < L_; l += 4) {
        const float* row = item_emb_table + (size_t)idx_sh[l] * D_;
        const float e = row[lane];
        float g0 = 0.f, g1 = 0.f, g2 = 0.f, g3 = 0.f;
#pragma unroll
        for (int kk = 0; kk < 16; ++kk) {
            const float4 e4 = ((const float4*)row)[kk];  // lane-uniform broadcast
            g0 = fmaf(e4.x, Wreg[4 * kk + 0], g0);
            g1 = fmaf(e4.y, Wreg[4 * kk + 1], g1);
            g2 = fmaf(e4.z, Wreg[4 * kk + 2], g2);
            g3 = fmaf(e4.w, Wreg[4 * kk + 3], g3);
        }
        const float gate = sigmoidf_(gbias + (g0 + g1) + (g2 + g3));
        gi_sh[l * 65 + lane] = e * gate;
        esum += e;
    }
    esum_sh[wave * 64 + lane] = esum;
    __syncthreads();   // gi_sh / esum_sh ready

    // ---- Phases B + C: wave 0 only
    if (wave == 0) {
        if (lane < L_) {           // B: instance score for l = lane
            float p0 = 0.f, p1 = 0.f, p2 = 0.f, p3 = 0.f;
#pragma unroll
            for (int d = 0; d < 64; d += 4) {
                p0 = fmaf(gi_sh[lane * 65 + d + 0], ig_item[d + 0], p0);
                p1 = fmaf(gi_sh[lane * 65 + d + 1], ig_item[d + 1], p1);
                p2 = fmaf(gi_sh[lane * 65 + d + 2], ig_item[d + 2], p2);
                p3 = fmaf(gi_sh[lane * 65 + d + 3], ig_item[d + 3], p3);
                p0 = fmaf(u_sh[d + 0], ig_user[(d + 0) * L_ + lane], p0);
                p1 = fmaf(u_sh[d + 1], ig_user[(d + 1) * L_ + lane], p1);
                p2 = fmaf(u_sh[d + 2], ig_user[(d + 2) * L_ + lane], p2);
                p3 = fmaf(u_sh[d + 3], ig_user[(d + 3) * L_ + lane], p3);
            }
            s_sh[lane] = sigmoidf_((p0 + p1) + (p2 + p3));
        }
        // C: same wave -> s_sh writes visible after lgkmcnt, no barrier needed
        float a0 = 0.f, a1 = 0.f, ss = 0.f;
        for (int l = 0; l < L_; l += 2) {
            const float sA = s_sh[l], sB = s_sh[l + 1];  // broadcast reads
            a0 = fmaf(gi_sh[l * 65 + lane], sA, a0);
            a1 = fmaf(gi_sh[(l + 1) * 65 + lane], sB, a1);
            ss += sA + sB;
        }
        const float es = esum_sh[lane] + esum_sh[64 + lane] +
                         esum_sh[128 + lane] + esum_sh[192 + lane];
        v_sh[lane] = u_sh[lane] + (a0 + a1) / ss + es;
    }
    __syncthreads();   // v_sh ready

    // ---- Phase D: scoring, one thread per t
    if (t < T_) {
        const int idx = items_to_predict[b * T_ + t];
        const float* wrow = W2 + (size_t)idx * D_;
        float r0 = 0.f, r1 = 0.f, r2 = 0.f, r3 = 0.f;
#pragma unroll
        for (int kk = 0; kk < 16; ++kk) {
            const float4 w4 = ((const float4*)wrow)[kk];       // per-lane gather
            const float4 v4 = ((const float4*)v_sh)[kk];       // LDS broadcast
            r0 = fmaf(v4.x, w4.x, r0);
            r1 = fmaf(v4.y, w4.y, r1);
            r2 = fmaf(v4.z, w4.z, r2);
            r3 = fmaf(v4.w, w4.w, r3);
        }
        out[b * T_ + t] = ((r0 + r1) + (r2 + r3)) + b2[idx];
    }
}

extern "C" void kernel_launch(void* const* d_in, const int* in_sizes, int n_in,
                              void* d_out, int out_size, void* d_ws, size_t ws_size,
                              hipStream_t stream) {
    const int*   item_seq   = (const int*)d_in[0];
    const int*   user_ids   = (const int*)d_in[1];
    const int*   items_pred = (const int*)d_in[2];
    const float* uet        = (const float*)d_in[3];
    const float* iet        = (const float*)d_in[4];
    const float* fgiW       = (const float*)d_in[5];
    const float* fgib       = (const float*)d_in[6];
    const float* fguW       = (const float*)d_in[7];
    const float* fgub       = (const float*)d_in[8];
    const float* igi        = (const float*)d_in[9];
    const float* igu        = (const float*)d_in[10];
    const float* W2         = (const float*)d_in[11];
    const float* b2t        = (const float*)d_in[12];

    hgn_fused_kernel<<<B_, 256, 0, stream>>>(
        item_seq, user_ids, items_pred, uet, iet,
        fgiW, fgib, fguW, fgub, igi, igu, W2, b2t, (float*)d_out);
}